// Round 1
// baseline (149.021 us; speedup 1.0000x reference)
//
#include <hip/hip_runtime.h>
#include <hip/hip_bf16.h>

typedef __attribute__((ext_vector_type(4))) float f32x4;
typedef __attribute__((ext_vector_type(8))) short bf16x8;
typedef __attribute__((ext_vector_type(4))) unsigned short u16x4;

#define DEVI __device__ __forceinline__

constexpr int B_ = 4, S_ = 1024, D_ = 512, H_ = 8, HD_ = 64;
constexpr float NEGV = -1e10f;

DEVI unsigned short f2b(float f) {
  union { float f; unsigned u; } v; v.f = f;
  unsigned r = v.u + 0x7fffu + ((v.u >> 16) & 1u);
  return (unsigned short)(r >> 16);
}

// ---------------- transpose + bf16-convert the 4 weight matrices ----------------
__global__ __launch_bounds__(256) void k_transpose(const float* W0, const float* W1,
                                                   const float* W2, const float* W3,
                                                   unsigned short* T0, unsigned short* T1,
                                                   unsigned short* T2, unsigned short* T3) {
  const float* W = blockIdx.z == 0 ? W0 : blockIdx.z == 1 ? W1 : blockIdx.z == 2 ? W2 : W3;
  unsigned short* T = blockIdx.z == 0 ? T0 : blockIdx.z == 1 ? T1 : blockIdx.z == 2 ? T2 : T3;
  __shared__ float tile[32][33];
  int tx = threadIdx.x & 31, ty = threadIdx.x >> 5;
  int n0 = blockIdx.x * 32, k0 = blockIdx.y * 32;
#pragma unroll
  for (int r = 0; r < 4; ++r) tile[ty + r * 8][tx] = W[(size_t)(k0 + ty + r * 8) * D_ + n0 + tx];
  __syncthreads();
#pragma unroll
  for (int r = 0; r < 4; ++r) T[(size_t)(n0 + ty + r * 8) * D_ + k0 + tx] = f2b(tile[tx][ty + r * 8]);
}

// ---------------- bias MLP on the 63x63 distinct relative offsets ----------------
__global__ __launch_bounds__(256) void k_bias_table(const float* W1, const float* b1,
                                                    const float* W2, const float* b2,
                                                    float* table) {
  int idx = blockIdx.x * 256 + threadIdx.x;
  if (idx >= 63 * 63) return;
  int dy = idx / 63 - 31, dx = idx % 63 - 31;
  float r0 = copysignf(log1pf(fabsf((float)dy)), (float)dy);
  float r1 = copysignf(log1pf(fabsf((float)dx)), (float)dx);
  float acc[8];
#pragma unroll
  for (int h = 0; h < 8; ++h) acc[h] = b2[h];
  for (int j = 0; j < 128; ++j) {
    float hv = fmaxf(r0 * W1[j] + r1 * W1[128 + j] + b1[j], 0.f);
#pragma unroll
    for (int h = 0; h < 8; ++h) acc[h] += hv * W2[j * 8 + h];
  }
#pragma unroll
  for (int h = 0; h < 8; ++h) table[h * 3969 + idx] = acc[h];
}

// ---------------- MFMA GEMM: [4096,512] @ BT[512,512]^T(+bias) ----------------
// MODE 0: A fp32, out bf16 scattered to [B,H,S,HD]  (QKV projection)
// MODE 1: A bf16, out fp32 row-major                (output projection)
template <int MODE>
__global__ __launch_bounds__(256) void k_gemm(const void* Ap, const unsigned short* BT,
                                              const float* bias, void* outp) {
  __shared__ unsigned short As[128][40];  // +8 pad: 80B row stride, conflict-free b128 reads
  __shared__ unsigned short Bs[128][40];
  const int tid = threadIdx.x;
  const int lane = tid & 63, wave = tid >> 6;
  const int lr = lane & 15, lg = lane >> 4;
  const int wm = (wave >> 1) * 64, wn = (wave & 1) * 64;
  const int m0 = blockIdx.x * 128, n0 = blockIdx.y * 128;

  f32x4 acc[4][4];
#pragma unroll
  for (int i = 0; i < 4; ++i)
#pragma unroll
    for (int j = 0; j < 4; ++j) acc[i][j] = (f32x4){0.f, 0.f, 0.f, 0.f};

  for (int k0 = 0; k0 < 512; k0 += 32) {
#pragma unroll
    for (int i = 0; i < 4; ++i) {
      int idx = tid + i * 256;
      int r = idx >> 3, c4 = (idx & 7) * 4;
      if (MODE == 0) {
        const float* A = (const float*)Ap;
        float4 fv = *(const float4*)(A + (size_t)(m0 + r) * 512 + k0 + c4);
        u16x4 w;
        w[0] = f2b(fv.x); w[1] = f2b(fv.y); w[2] = f2b(fv.z); w[3] = f2b(fv.w);
        *(u16x4*)&As[r][c4] = w;
      } else {
        const unsigned short* A = (const unsigned short*)Ap;
        *(u16x4*)&As[r][c4] = *(const u16x4*)(A + (size_t)(m0 + r) * 512 + k0 + c4);
      }
      *(u16x4*)&Bs[r][c4] = *(const u16x4*)(BT + (size_t)(n0 + r) * 512 + k0 + c4);
    }
    __syncthreads();
    bf16x8 af[4], bg[4];
#pragma unroll
    for (int i = 0; i < 4; ++i) af[i] = *(const bf16x8*)&As[wm + i * 16 + lr][lg * 8];
#pragma unroll
    for (int j = 0; j < 4; ++j) bg[j] = *(const bf16x8*)&Bs[wn + j * 16 + lr][lg * 8];
#pragma unroll
    for (int i = 0; i < 4; ++i)
#pragma unroll
      for (int j = 0; j < 4; ++j)
        acc[i][j] = __builtin_amdgcn_mfma_f32_16x16x32_bf16(af[i], bg[j], acc[i][j], 0, 0, 0);
    __syncthreads();
  }

#pragma unroll
  for (int i = 0; i < 4; ++i)
#pragma unroll
    for (int j = 0; j < 4; ++j) {
      int mbase = m0 + wm + i * 16 + lg * 4;
      int n = n0 + wn + j * 16 + lr;
      float bv = bias[n];
#pragma unroll
      for (int r = 0; r < 4; ++r) {
        int m = mbase + r;
        float v = acc[i][j][r] + bv;
        if (MODE == 0) {
          int b = m >> 10, s = m & 1023, h = n >> 6, hd = n & 63;
          ((unsigned short*)outp)[(((size_t)b * H_ + h) * S_ + s) * HD_ + hd] = f2b(v);
        } else {
          ((float*)outp)[(size_t)m * 512 + n] = v;
        }
      }
    }
}

// ---------------- fused two-pass attention ----------------
// block = (b,h,q-tile of 64 rows), 4 waves (16 q-rows each), 256 threads
__global__ __launch_bounds__(256) void k_attn(const unsigned short* Qb, const unsigned short* Kb,
                                              const unsigned short* Vb, const float* table,
                                              const int* mask, float* out_attn,
                                              unsigned short* Xp) {
  const int tid = threadIdx.x;
  const int lane = tid & 63, w = tid >> 6;
  const int lr = lane & 15, lg = lane >> 4;
  const int bh = blockIdx.y, b = bh >> 3, h = bh & 7;
  const int q0 = blockIdx.x * 64;

  __shared__ unsigned short Ks[64][64];      // K tile, XOR-swizzled 16B chunks
  __shared__ unsigned short Vt[64][64];      // V^T tile, XOR-swizzled
  __shared__ unsigned short Pl[4][16][64];   // per-wave P tile, XOR-swizzled
  __shared__ float biasT[3969];
  __shared__ float mval[1024];

  const unsigned short* Qh = Qb + (size_t)bh * S_ * HD_;
  const unsigned short* Kh = Kb + (size_t)bh * S_ * HD_;
  const unsigned short* Vh = Vb + (size_t)bh * S_ * HD_;

  for (int i = tid; i < 3969; i += 256) biasT[i] = table[(size_t)h * 3969 + i];
  for (int i = tid; i < 1024; i += 256) mval[i] = (mask[b * S_ + i] == 0) ? 0.f : 1.f;

  const int qrow = q0 + w * 16 + lr;
  bf16x8 aq0 = *(const bf16x8*)(Qh + (size_t)qrow * 64 + lg * 8);
  bf16x8 aq1 = *(const bf16x8*)(Qh + (size_t)qrow * 64 + 32 + lg * 8);

  const int qg = q0 + w * 16 + lg * 4;  // base row for this lane's D-fragment rows

  float lm[4], ls[4];
#pragma unroll
  for (int r = 0; r < 4; ++r) { lm[r] = -3.0e38f; ls[r] = 0.f; }

  // ---- PASS 1: row max / sum ----
  for (int kt = 0; kt < 16; ++kt) {
    __syncthreads();
#pragma unroll
    for (int i = 0; i < 2; ++i) {
      int idx = tid + i * 256;
      int row = idx >> 3, c8 = idx & 7;
      bf16x8 v = *(const bf16x8*)(Kh + (size_t)(kt * 64 + row) * 64 + c8 * 8);
      *(bf16x8*)&Ks[row][(c8 ^ (row & 7)) * 8] = v;
    }
    __syncthreads();
    f32x4 sf[4];
#pragma unroll
    for (int fn = 0; fn < 4; ++fn) {
      int kr = fn * 16 + lr;
      bf16x8 b0 = *(const bf16x8*)&Ks[kr][(lg ^ (kr & 7)) * 8];
      bf16x8 b1 = *(const bf16x8*)&Ks[kr][((4 + lg) ^ (kr & 7)) * 8];
      f32x4 s = (f32x4){0.f, 0.f, 0.f, 0.f};
      s = __builtin_amdgcn_mfma_f32_16x16x32_bf16(aq0, b0, s, 0, 0, 0);
      s = __builtin_amdgcn_mfma_f32_16x16x32_bf16(aq1, b1, s, 0, 0, 0);
      sf[fn] = s;
    }
#pragma unroll
    for (int r = 0; r < 4; ++r) {
      int q = qg + r;
      int qi = q >> 5, qj = q & 31;
      float e[4];
#pragma unroll
      for (int fn = 0; fn < 4; ++fn) {
        int kc = kt * 64 + fn * 16 + lr;
        int ki = kc >> 5, kj = kc & 31;
        float ev = sf[fn][r] * 0.125f + biasT[(qi - ki + 31) * 63 + (qj - kj + 31)];
        e[fn] = (mval[kc] != 0.f) ? ev : NEGV;
      }
      float tmax = fmaxf(fmaxf(e[0], e[1]), fmaxf(e[2], e[3]));
      float mnew = fmaxf(lm[r], tmax);
      float ssum = __expf(e[0] - mnew) + __expf(e[1] - mnew) +
                   __expf(e[2] - mnew) + __expf(e[3] - mnew);
      ls[r] = ls[r] * __expf(lm[r] - mnew) + ssum;
      lm[r] = mnew;
    }
  }
  // merge (m,l) across the 16 lanes holding different k-columns of the same rows
  float inv[4];
#pragma unroll
  for (int r = 0; r < 4; ++r) {
#pragma unroll
    for (int d = 1; d < 16; d <<= 1) {
      float om = __shfl_xor(lm[r], d, 64);
      float os = __shfl_xor(ls[r], d, 64);
      float mn = fmaxf(lm[r], om);
      ls[r] = ls[r] * __expf(lm[r] - mn) + os * __expf(om - mn);
      lm[r] = mn;
    }
    inv[r] = 1.f / ls[r];
  }

  // ---- PASS 2: recompute, write attention, accumulate PV ----
  f32x4 of[4];
#pragma unroll
  for (int fn = 0; fn < 4; ++fn) of[fn] = (f32x4){0.f, 0.f, 0.f, 0.f};
  float* oa = out_attn + (size_t)bh * S_ * S_;

  for (int kt = 0; kt < 16; ++kt) {
    __syncthreads();
#pragma unroll
    for (int i = 0; i < 2; ++i) {  // K tile
      int idx = tid + i * 256;
      int row = idx >> 3, c8 = idx & 7;
      bf16x8 v = *(const bf16x8*)(Kh + (size_t)(kt * 64 + row) * 64 + c8 * 8);
      *(bf16x8*)&Ks[row][(c8 ^ (row & 7)) * 8] = v;
    }
#pragma unroll
    for (int i = 0; i < 2; ++i) {  // V^T tile (transpose during staging)
      int task = tid + i * 256;
      int hd = task & 63, ch = task >> 6;
      unsigned short tmp[8];
#pragma unroll
      for (int j = 0; j < 8; ++j) tmp[j] = Vh[(size_t)(kt * 64 + ch * 8 + j) * 64 + hd];
      *(bf16x8*)&Vt[hd][(ch ^ (hd & 7)) * 8] = *(bf16x8*)tmp;
    }
    __syncthreads();
#pragma unroll
    for (int fn = 0; fn < 4; ++fn) {
      int kr = fn * 16 + lr;
      bf16x8 b0 = *(const bf16x8*)&Ks[kr][(lg ^ (kr & 7)) * 8];
      bf16x8 b1 = *(const bf16x8*)&Ks[kr][((4 + lg) ^ (kr & 7)) * 8];
      f32x4 s = (f32x4){0.f, 0.f, 0.f, 0.f};
      s = __builtin_amdgcn_mfma_f32_16x16x32_bf16(aq0, b0, s, 0, 0, 0);
      s = __builtin_amdgcn_mfma_f32_16x16x32_bf16(aq1, b1, s, 0, 0, 0);
#pragma unroll
      for (int r = 0; r < 4; ++r) {
        int q = qg + r;
        int qi = q >> 5, qj = q & 31;
        int kc = kt * 64 + fn * 16 + lr;
        int ki = kc >> 5, kj = kc & 31;
        float ev = s[r] * 0.125f + biasT[(qi - ki + 31) * 63 + (qj - kj + 31)];
        ev = (mval[kc] != 0.f) ? ev : NEGV;
        float p = __expf(ev - lm[r]) * inv[r];
        oa[(size_t)q * S_ + kc] = p;
        int lrow = lg * 4 + r;
        int ch2 = fn * 2 + (lr >> 3);
        Pl[w][lrow][((ch2 ^ (lrow & 7)) * 8) + (lr & 7)] = f2b(p);
      }
    }
    // PV: O += P @ V   (same-wave LDS dependency; compiler inserts lgkmcnt waits)
#pragma unroll
    for (int fn = 0; fn < 4; ++fn) {
      int vr = fn * 16 + lr;
      bf16x8 bv0 = *(const bf16x8*)&Vt[vr][(lg ^ (vr & 7)) * 8];
      bf16x8 bv1 = *(const bf16x8*)&Vt[vr][((4 + lg) ^ (vr & 7)) * 8];
      bf16x8 pa0 = *(const bf16x8*)&Pl[w][lr][(lg ^ (lr & 7)) * 8];
      bf16x8 pa1 = *(const bf16x8*)&Pl[w][lr][((4 + lg) ^ (lr & 7)) * 8];
      of[fn] = __builtin_amdgcn_mfma_f32_16x16x32_bf16(pa0, bv0, of[fn], 0, 0, 0);
      of[fn] = __builtin_amdgcn_mfma_f32_16x16x32_bf16(pa1, bv1, of[fn], 0, 0, 0);
    }
  }

  // epilogue: x pre-projection in [B,S,H*HD] layout, bf16
#pragma unroll
  for (int fn = 0; fn < 4; ++fn)
#pragma unroll
    for (int r = 0; r < 4; ++r) {
      int q = qg + r;
      int hd = fn * 16 + lr;
      Xp[((size_t)b * S_ + q) * D_ + h * HD_ + hd] = f2b(of[fn][r]);
    }
}

// ---------------- host launch ----------------
extern "C" void kernel_launch(void* const* d_in, const int* in_sizes, int n_in,
                              void* d_out, int out_size, void* d_ws, size_t ws_size,
                              hipStream_t stream) {
  const float* query = (const float*)d_in[0];
  const float* key   = (const float*)d_in[1];
  const float* value = (const float*)d_in[2];
  const int*   maskp = (const int*)d_in[3];
  const float* Wq = (const float*)d_in[4];
  const float* bq = (const float*)d_in[5];
  const float* Wk = (const float*)d_in[6];
  const float* bk = (const float*)d_in[7];
  const float* Wv = (const float*)d_in[8];
  const float* bv = (const float*)d_in[9];
  const float* Wo = (const float*)d_in[10];
  const float* bo = (const float*)d_in[11];
  const float* W1 = (const float*)d_in[12];
  const float* b1 = (const float*)d_in[13];
  const float* W2 = (const float*)d_in[14];
  const float* b2 = (const float*)d_in[15];

  char* ws = (char*)d_ws;
  const size_t QKV_BYTES = (size_t)B_ * H_ * S_ * HD_ * 2;  // 4 MB each
  unsigned short* Qb = (unsigned short*)(ws);
  unsigned short* Kb = (unsigned short*)(ws + QKV_BYTES);
  unsigned short* Vb = (unsigned short*)(ws + 2 * QKV_BYTES);
  unsigned short* WqT = (unsigned short*)(ws + 3 * QKV_BYTES);
  unsigned short* WkT = (unsigned short*)(ws + 3 * QKV_BYTES + 524288);
  unsigned short* WvT = (unsigned short*)(ws + 3 * QKV_BYTES + 2 * 524288);
  unsigned short* WoT = (unsigned short*)(ws + 3 * QKV_BYTES + 3 * 524288);
  float* table = (float*)(ws + 3 * QKV_BYTES + 4 * 524288);
  unsigned short* Xp = (unsigned short*)(ws + 3 * QKV_BYTES + 4 * 524288 + 131072);

  float* out_x = (float*)d_out;
  float* out_attn = out_x + (size_t)B_ * S_ * D_;

  k_transpose<<<dim3(16, 16, 4), 256, 0, stream>>>(Wq, Wk, Wv, Wo, WqT, WkT, WvT, WoT);
  k_bias_table<<<dim3(16), 256, 0, stream>>>(W1, b1, W2, b2, table);
  k_gemm<0><<<dim3(32, 4), 256, 0, stream>>>(query, WqT, bq, Qb);
  k_gemm<0><<<dim3(32, 4), 256, 0, stream>>>(key, WkT, bk, Kb);
  k_gemm<0><<<dim3(32, 4), 256, 0, stream>>>(value, WvT, bv, Vb);
  k_attn<<<dim3(16, 32), 256, 0, stream>>>(Qb, Kb, Vb, table, maskp, out_attn, Xp);
  k_gemm<1><<<dim3(32, 4), 256, 0, stream>>>(Xp, WoT, bo, out_x);
}

// Round 2
// 110.587 us; speedup vs baseline: 1.3475x; 1.3475x over previous
//
#include <hip/hip_runtime.h>
#include <hip/hip_bf16.h>

typedef __attribute__((ext_vector_type(4))) float f32x4;
typedef __attribute__((ext_vector_type(8))) short bf16x8;
typedef __attribute__((ext_vector_type(4))) unsigned short u16x4;

#define DEVI __device__ __forceinline__

constexpr int B_ = 4, S_ = 1024, D_ = 512, H_ = 8, HD_ = 64;
constexpr float NEGV = -1e10f;

DEVI unsigned short f2b(float f) {
  union { float f; unsigned u; } v; v.f = f;
  unsigned r = v.u + 0x7fffu + ((v.u >> 16) & 1u);
  return (unsigned short)(r >> 16);
}

// ---------------- prep: weight transpose+bf16 (z=0..3) and bias MLP table (z=4) ----------------
__global__ __launch_bounds__(256) void k_prep(const float* Wa, const float* Wb,
                                              const float* Wc, const float* Wd,
                                              unsigned short* T0, unsigned short* T1,
                                              unsigned short* T2, unsigned short* T3,
                                              const float* mW1, const float* mb1,
                                              const float* mW2, const float* mb2,
                                              float* table) {
  if (blockIdx.z == 4) {
    if (blockIdx.y != 0) return;
    int idx = blockIdx.x * 256 + threadIdx.x;
    if (idx >= 63 * 63) return;
    int dy = idx / 63 - 31, dx = idx % 63 - 31;
    float r0 = copysignf(log1pf(fabsf((float)dy)), (float)dy);
    float r1 = copysignf(log1pf(fabsf((float)dx)), (float)dx);
    float acc[8];
#pragma unroll
    for (int h = 0; h < 8; ++h) acc[h] = mb2[h];
    for (int j = 0; j < 128; ++j) {
      float hv = fmaxf(r0 * mW1[j] + r1 * mW1[128 + j] + mb1[j], 0.f);
#pragma unroll
      for (int h = 0; h < 8; ++h) acc[h] += hv * mW2[j * 8 + h];
    }
#pragma unroll
    for (int h = 0; h < 8; ++h) table[h * 3969 + idx] = acc[h];
    return;
  }
  const float* W = blockIdx.z == 0 ? Wa : blockIdx.z == 1 ? Wb : blockIdx.z == 2 ? Wc : Wd;
  unsigned short* T = blockIdx.z == 0 ? T0 : blockIdx.z == 1 ? T1 : blockIdx.z == 2 ? T2 : T3;
  __shared__ float tile[32][33];
  int tx = threadIdx.x & 31, ty = threadIdx.x >> 5;
  int n0 = blockIdx.x * 32, k0 = blockIdx.y * 32;
#pragma unroll
  for (int r = 0; r < 4; ++r) tile[ty + r * 8][tx] = W[(size_t)(k0 + ty + r * 8) * D_ + n0 + tx];
  __syncthreads();
#pragma unroll
  for (int r = 0; r < 4; ++r) T[(size_t)(n0 + ty + r * 8) * D_ + k0 + tx] = f2b(tile[tx][ty + r * 8]);
}

// ---------------- merged QKV projection GEMM: [4096,512] @ W^T + bias -> bf16 [B,H,S,HD] ----------------
__global__ __launch_bounds__(256) void k_gemm_qkv(const float* Aq, const float* Ak, const float* Av,
                                                  const unsigned short* Tq, const unsigned short* Tk,
                                                  const unsigned short* Tv,
                                                  const float* bqv, const float* bkv, const float* bvv,
                                                  unsigned short* Oq, unsigned short* Ok,
                                                  unsigned short* Ov) {
  const float* A = blockIdx.z == 0 ? Aq : blockIdx.z == 1 ? Ak : Av;
  const unsigned short* BT = blockIdx.z == 0 ? Tq : blockIdx.z == 1 ? Tk : Tv;
  const float* bias = blockIdx.z == 0 ? bqv : blockIdx.z == 1 ? bkv : bvv;
  unsigned short* outp = blockIdx.z == 0 ? Oq : blockIdx.z == 1 ? Ok : Ov;

  __shared__ unsigned short As[128][40];
  __shared__ unsigned short Bs[128][40];
  const int tid = threadIdx.x;
  const int lane = tid & 63, wave = tid >> 6;
  const int lr = lane & 15, lg = lane >> 4;
  const int wm = (wave >> 1) * 64, wn = (wave & 1) * 64;
  const int m0 = blockIdx.x * 128, n0 = blockIdx.y * 128;

  f32x4 acc[4][4];
#pragma unroll
  for (int i = 0; i < 4; ++i)
#pragma unroll
    for (int j = 0; j < 4; ++j) acc[i][j] = (f32x4){0.f, 0.f, 0.f, 0.f};

  for (int k0 = 0; k0 < 512; k0 += 32) {
#pragma unroll
    for (int i = 0; i < 4; ++i) {
      int idx = tid + i * 256;
      int r = idx >> 3, c4 = (idx & 7) * 4;
      float4 fv = *(const float4*)(A + (size_t)(m0 + r) * 512 + k0 + c4);
      u16x4 wv;
      wv[0] = f2b(fv.x); wv[1] = f2b(fv.y); wv[2] = f2b(fv.z); wv[3] = f2b(fv.w);
      *(u16x4*)&As[r][c4] = wv;
      *(u16x4*)&Bs[r][c4] = *(const u16x4*)(BT + (size_t)(n0 + r) * 512 + k0 + c4);
    }
    __syncthreads();
    bf16x8 af[4], bg[4];
#pragma unroll
    for (int i = 0; i < 4; ++i) af[i] = *(const bf16x8*)&As[wm + i * 16 + lr][lg * 8];
#pragma unroll
    for (int j = 0; j < 4; ++j) bg[j] = *(const bf16x8*)&Bs[wn + j * 16 + lr][lg * 8];
#pragma unroll
    for (int i = 0; i < 4; ++i)
#pragma unroll
      for (int j = 0; j < 4; ++j)
        acc[i][j] = __builtin_amdgcn_mfma_f32_16x16x32_bf16(af[i], bg[j], acc[i][j], 0, 0, 0);
    __syncthreads();
  }

#pragma unroll
  for (int i = 0; i < 4; ++i)
#pragma unroll
    for (int j = 0; j < 4; ++j) {
      int mbase = m0 + wm + i * 16 + lg * 4;
      int n = n0 + wn + j * 16 + lr;
      float bvl = bias[n];
#pragma unroll
      for (int r = 0; r < 4; ++r) {
        int m = mbase + r;
        float v = acc[i][j][r] + bvl;
        int b = m >> 10, s = m & 1023, h = n >> 6, hd = n & 63;
        outp[(((size_t)b * H_ + h) * S_ + s) * HD_ + hd] = f2b(v);
      }
    }
}

// ---------------- output projection GEMM: bf16 A @ W^T + bias -> fp32 ----------------
__global__ __launch_bounds__(256) void k_gemm_out(const unsigned short* A, const unsigned short* BT,
                                                  const float* bias, float* outp) {
  __shared__ unsigned short As[128][40];
  __shared__ unsigned short Bs[128][40];
  const int tid = threadIdx.x;
  const int lane = tid & 63, wave = tid >> 6;
  const int lr = lane & 15, lg = lane >> 4;
  const int wm = (wave >> 1) * 64, wn = (wave & 1) * 64;
  const int m0 = blockIdx.x * 128, n0 = blockIdx.y * 128;

  f32x4 acc[4][4];
#pragma unroll
  for (int i = 0; i < 4; ++i)
#pragma unroll
    for (int j = 0; j < 4; ++j) acc[i][j] = (f32x4){0.f, 0.f, 0.f, 0.f};

  for (int k0 = 0; k0 < 512; k0 += 32) {
#pragma unroll
    for (int i = 0; i < 4; ++i) {
      int idx = tid + i * 256;
      int r = idx >> 3, c4 = (idx & 7) * 4;
      *(u16x4*)&As[r][c4] = *(const u16x4*)(A + (size_t)(m0 + r) * 512 + k0 + c4);
      *(u16x4*)&Bs[r][c4] = *(const u16x4*)(BT + (size_t)(n0 + r) * 512 + k0 + c4);
    }
    __syncthreads();
    bf16x8 af[4], bg[4];
#pragma unroll
    for (int i = 0; i < 4; ++i) af[i] = *(const bf16x8*)&As[wm + i * 16 + lr][lg * 8];
#pragma unroll
    for (int j = 0; j < 4; ++j) bg[j] = *(const bf16x8*)&Bs[wn + j * 16 + lr][lg * 8];
#pragma unroll
    for (int i = 0; i < 4; ++i)
#pragma unroll
      for (int j = 0; j < 4; ++j)
        acc[i][j] = __builtin_amdgcn_mfma_f32_16x16x32_bf16(af[i], bg[j], acc[i][j], 0, 0, 0);
    __syncthreads();
  }

#pragma unroll
  for (int i = 0; i < 4; ++i)
#pragma unroll
    for (int j = 0; j < 4; ++j) {
      int mbase = m0 + wm + i * 16 + lg * 4;
      int n = n0 + wn + j * 16 + lr;
      float bvl = bias[n];
#pragma unroll
      for (int r = 0; r < 4; ++r)
        outp[(size_t)(mbase + r) * 512 + n] = acc[i][j][r] + bvl;
    }
}

// ---------------- V transpose: [B,H,S,HD] -> [B,H,HD,S] (bf16) ----------------
__global__ __launch_bounds__(256) void k_vtrans(const unsigned short* Vb, unsigned short* VT) {
  __shared__ unsigned int tile[64 * 33];
  const int tid = threadIdx.x;
  const int bh = blockIdx.y;
  const int s0 = blockIdx.x * 64;
  const unsigned int* src = (const unsigned int*)(Vb + (size_t)bh * S_ * HD_);
#pragma unroll
  for (int i = 0; i < 8; ++i) {
    int idx = tid + i * 256;
    int row = idx >> 5, t = idx & 31;
    tile[row * 33 + t] = src[(size_t)(s0 + row) * 32 + t];
  }
  __syncthreads();
#pragma unroll
  for (int i = 0; i < 2; ++i) {
    int slot = tid + i * 256;
    int d = slot >> 3, ck = slot & 7;
    int t = d >> 1, hs = (d & 1) * 16;
    bf16x8 tv;
#pragma unroll
    for (int j = 0; j < 8; ++j) tv[j] = (short)(tile[(ck * 8 + j) * 33 + t] >> hs);
    *(bf16x8*)(VT + ((size_t)bh * 64 + d) * S_ + s0 + ck * 8) = tv;
  }
}

// ---------------- fused two-pass attention (swapped QK^T: S^T fragments) ----------------
// block = (q-tile 64, bh); 4 waves; wave w owns q rows [q0+16w, q0+16w+16); lane owns row q0+16w+lr
__global__ __launch_bounds__(256) void k_attn(const unsigned short* Qb, const unsigned short* Kb,
                                              const unsigned short* VT, const float* table,
                                              const int* mask, float* out_attn,
                                              unsigned short* Xp) {
  const int tid = threadIdx.x;
  const int lane = tid & 63, w = tid >> 6;
  const int lr = lane & 15, lg = lane >> 4;
  const int bh = blockIdx.y, b = bh >> 3, h = bh & 7;
  const int q0 = blockIdx.x * 64;

  __shared__ unsigned short Ks[64][64];     // K tile, 16B chunks XOR-swizzled by row&7
  __shared__ unsigned short Vt[64][64];     // V^T tile, same swizzle
  __shared__ unsigned short Pl[4][16][64];  // per-wave P tile (bf16), 16B-chunk swizzle
  __shared__ float biasT[3969];
  __shared__ float mval[1024];

  const unsigned short* Qh = Qb + (size_t)bh * S_ * HD_;
  const unsigned short* Kh = Kb + (size_t)bh * S_ * HD_;
  const unsigned short* Vth = VT + (size_t)bh * HD_ * S_;

  for (int i = tid; i < 3969; i += 256) biasT[i] = table[h * 3969 + i];
  for (int i = tid; i < 1024; i += 256) mval[i] = (mask[b * S_ + i] == 0) ? 0.f : 1.f;

  const int qrow = q0 + w * 16 + lr;
  const bf16x8 bq0 = *(const bf16x8*)(Qh + (size_t)qrow * 64 + lg * 8);
  const bf16x8 bq1 = *(const bf16x8*)(Qh + (size_t)qrow * 64 + 32 + lg * 8);
  // bias index: (qi-ki+31)*63 + (qj-kj+31) == qterm - k - 31*(k>>5)
  const int qterm = (qrow >> 5) * 63 + (qrow & 31) + 1984;

  float lm = -3.0e38f, ls = 0.f;

  // ---- PASS 1: row max / sum ----
  for (int kt = 0; kt < 16; ++kt) {
    __syncthreads();
#pragma unroll
    for (int i = 0; i < 2; ++i) {
      int slot = tid + i * 256;
      int row = slot >> 3, c = slot & 7;
      bf16x8 v = *(const bf16x8*)(Kh + (size_t)(kt * 64 + row) * 64 + c * 8);
      *(bf16x8*)&Ks[row][(c ^ (row & 7)) * 8] = v;
    }
    __syncthreads();
    const int bidx = qterm - 126 * kt;
    float es[16];
    float emax = -3.0e38f;
#pragma unroll
    for (int fn = 0; fn < 4; ++fn) {
      const unsigned short* krow = &Ks[fn * 16 + lr][0];
      bf16x8 a0 = *(const bf16x8*)(krow + (lg ^ (lr & 7)) * 8);
      bf16x8 a1 = *(const bf16x8*)(krow + ((4 + lg) ^ (lr & 7)) * 8);
      f32x4 s = (f32x4){0.f, 0.f, 0.f, 0.f};
      s = __builtin_amdgcn_mfma_f32_16x16x32_bf16(a0, bq0, s, 0, 0, 0);
      s = __builtin_amdgcn_mfma_f32_16x16x32_bf16(a1, bq1, s, 0, 0, 0);
#pragma unroll
      for (int r = 0; r < 4; ++r) {
        int ko = fn * 16 + lg * 4 + r;
        float ev = s[r] * 0.125f + biasT[bidx - ko - (fn >= 2 ? 31 : 0)];
        ev = (mval[kt * 64 + ko] != 0.f) ? ev : NEGV;
        es[fn * 4 + r] = ev;
        emax = fmaxf(emax, ev);
      }
    }
    float mnew = fmaxf(lm, emax);
    float sum = 0.f;
#pragma unroll
    for (int t = 0; t < 16; ++t) sum += __expf(es[t] - mnew);
    ls = ls * __expf(lm - mnew) + sum;
    lm = mnew;
  }
  // merge across lg groups: lanes {lr, lr+16, lr+32, lr+48} share a q-row
#pragma unroll
  for (int d = 16; d < 64; d <<= 1) {
    float om = __shfl_xor(lm, d, 64);
    float os = __shfl_xor(ls, d, 64);
    float mn = fmaxf(lm, om);
    ls = ls * __expf(lm - mn) + os * __expf(om - mn);
    lm = mn;
  }
  const float inv = 1.f / ls;

  // ---- PASS 2: recompute, write attention (float4), accumulate PV ----
  f32x4 of[4];
#pragma unroll
  for (int i = 0; i < 4; ++i) of[i] = (f32x4){0.f, 0.f, 0.f, 0.f};
  float* oa = out_attn + (size_t)bh * S_ * S_ + (size_t)qrow * S_;

  for (int kt = 0; kt < 16; ++kt) {
    __syncthreads();
#pragma unroll
    for (int i = 0; i < 2; ++i) {
      int slot = tid + i * 256;
      int row = slot >> 3, c = slot & 7;
      bf16x8 v = *(const bf16x8*)(Kh + (size_t)(kt * 64 + row) * 64 + c * 8);
      *(bf16x8*)&Ks[row][(c ^ (row & 7)) * 8] = v;
    }
#pragma unroll
    for (int i = 0; i < 2; ++i) {
      int slot = tid + i * 256;
      int row = slot >> 3, c = slot & 7;
      bf16x8 v = *(const bf16x8*)(Vth + (size_t)row * S_ + kt * 64 + c * 8);
      *(bf16x8*)&Vt[row][(c ^ (row & 7)) * 8] = v;
    }
    __syncthreads();
    const int bidx = qterm - 126 * kt;
#pragma unroll
    for (int fn = 0; fn < 4; ++fn) {
      const unsigned short* krow = &Ks[fn * 16 + lr][0];
      bf16x8 a0 = *(const bf16x8*)(krow + (lg ^ (lr & 7)) * 8);
      bf16x8 a1 = *(const bf16x8*)(krow + ((4 + lg) ^ (lr & 7)) * 8);
      f32x4 s = (f32x4){0.f, 0.f, 0.f, 0.f};
      s = __builtin_amdgcn_mfma_f32_16x16x32_bf16(a0, bq0, s, 0, 0, 0);
      s = __builtin_amdgcn_mfma_f32_16x16x32_bf16(a1, bq1, s, 0, 0, 0);
      f32x4 pv;
      u16x4 pb;
#pragma unroll
      for (int r = 0; r < 4; ++r) {
        int ko = fn * 16 + lg * 4 + r;
        float ev = s[r] * 0.125f + biasT[bidx - ko - (fn >= 2 ? 31 : 0)];
        ev = (mval[kt * 64 + ko] != 0.f) ? ev : NEGV;
        float p = __expf(ev - lm) * inv;
        pv[r] = p;
        pb[r] = f2b(p);
      }
      *(f32x4*)(oa + kt * 64 + fn * 16 + lg * 4) = pv;
      *(u16x4*)((char*)&Pl[w][lr][0] + ((fn * 2 + (lg >> 1)) ^ (lr & 7)) * 16 + (lg & 1) * 8) = pb;
    }
    // PV: O[q][d] += P[q][k] V[k][d]
#pragma unroll
    for (int c = 0; c < 2; ++c) {
      bf16x8 pa = *(const bf16x8*)((const char*)&Pl[w][lr][0] + ((c * 4 + lg) ^ (lr & 7)) * 16);
#pragma unroll
      for (int fn2 = 0; fn2 < 4; ++fn2) {
        bf16x8 bv = *(const bf16x8*)((const char*)&Vt[fn2 * 16 + lr][0] + ((c * 4 + lg) ^ (lr & 7)) * 16);
        of[fn2] = __builtin_amdgcn_mfma_f32_16x16x32_bf16(pa, bv, of[fn2], 0, 0, 0);
      }
    }
  }

  // epilogue: x pre-projection, bf16 [B,S,D]; lane holds O[q0+16w+4lg+r][16*fn2+lr]
#pragma unroll
  for (int fn2 = 0; fn2 < 4; ++fn2)
#pragma unroll
    for (int r = 0; r < 4; ++r) {
      int q = q0 + w * 16 + lg * 4 + r;
      Xp[((size_t)b * S_ + q) * D_ + h * 64 + fn2 * 16 + lr] = f2b(of[fn2][r]);
    }
}

// ---------------- host launch ----------------
extern "C" void kernel_launch(void* const* d_in, const int* in_sizes, int n_in,
                              void* d_out, int out_size, void* d_ws, size_t ws_size,
                              hipStream_t stream) {
  const float* query = (const float*)d_in[0];
  const float* key   = (const float*)d_in[1];
  const float* value = (const float*)d_in[2];
  const int*   maskp = (const int*)d_in[3];
  const float* Wq = (const float*)d_in[4];
  const float* bq = (const float*)d_in[5];
  const float* Wk = (const float*)d_in[6];
  const float* bk = (const float*)d_in[7];
  const float* Wv = (const float*)d_in[8];
  const float* bv = (const float*)d_in[9];
  const float* Wo = (const float*)d_in[10];
  const float* bo = (const float*)d_in[11];
  const float* W1 = (const float*)d_in[12];
  const float* b1 = (const float*)d_in[13];
  const float* W2 = (const float*)d_in[14];
  const float* b2 = (const float*)d_in[15];

  char* ws = (char*)d_ws;
  const size_t MB4 = (size_t)4 * 1024 * 1024;
  unsigned short* Qb  = (unsigned short*)(ws);
  unsigned short* Kb  = (unsigned short*)(ws + MB4);
  unsigned short* Vb  = (unsigned short*)(ws + 2 * MB4);
  unsigned short* VT  = (unsigned short*)(ws + 3 * MB4);
  unsigned short* WqT = (unsigned short*)(ws + 4 * MB4);
  unsigned short* WkT = (unsigned short*)(ws + 4 * MB4 + 524288);
  unsigned short* WvT = (unsigned short*)(ws + 4 * MB4 + 2 * 524288);
  unsigned short* WoT = (unsigned short*)(ws + 4 * MB4 + 3 * 524288);
  float* table        = (float*)(ws + 4 * MB4 + 4 * 524288);
  unsigned short* Xp  = Vb;  // Vb dead after k_vtrans; reuse for attention output

  float* out_x = (float*)d_out;
  float* out_attn = out_x + (size_t)B_ * S_ * D_;

  k_prep<<<dim3(16, 16, 5), 256, 0, stream>>>(Wq, Wk, Wv, Wo, WqT, WkT, WvT, WoT,
                                              W1, b1, W2, b2, table);
  k_gemm_qkv<<<dim3(32, 4, 3), 256, 0, stream>>>(query, key, value, WqT, WkT, WvT,
                                                 bq, bk, bv, Qb, Kb, Vb);
  k_vtrans<<<dim3(16, 32), 256, 0, stream>>>(Vb, VT);
  k_attn<<<dim3(16, 32), 256, 0, stream>>>(Qb, Kb, VT, table, maskp, out_attn, Xp);
  k_gemm_out<<<dim3(32, 4), 256, 0, stream>>>(Xp, WoT, bo, out_x);
}